// Round 3
// baseline (196.144 us; speedup 1.0000x reference)
//
#include <hip/hip_runtime.h>
#include <hip/hip_bf16.h>

#define EMBED 1024
#define HEADS 16
#define HDIM  64
#define BATCH 4
#define SEQ   1024

typedef __attribute__((ext_vector_type(8))) short  short8;
typedef __attribute__((ext_vector_type(4))) short  short4v;
typedef __attribute__((ext_vector_type(4))) float  float4v;

// f32 -> bf16 (RNE)
static __device__ __forceinline__ short f2b(float f) {
  unsigned u = __builtin_bit_cast(unsigned, f);
  unsigned r = (u + 0x7FFFu + ((u >> 16) & 1u)) >> 16;
  return (short)(unsigned short)r;
}

// pack two f32 -> bf16x2 (RNE) in one dword (lo = a, hi = b)
static __device__ __forceinline__ unsigned pkbf(float a, float b) {
  return (unsigned)(unsigned short)f2b(a) |
         ((unsigned)(unsigned short)f2b(b) << 16);
}

static __device__ __forceinline__ short8 cvt8(const float* p) {
  float4v a = *(const float4v*)p;
  float4v b = *(const float4v*)(p + 4);
  short8 r;
  r[0]=f2b(a[0]); r[1]=f2b(a[1]); r[2]=f2b(a[2]); r[3]=f2b(a[3]);
  r[4]=f2b(b[0]); r[5]=f2b(b[1]); r[6]=f2b(b[2]); r[7]=f2b(b[3]);
  return r;
}

// ---------------------------------------------------------------------------
// Kernel 1: per-head projections q/k/v.  1 wave per (16 rows, head, tensor).
// out[s][o] = sum_d in[s][h*64+d] * W[o][d]   (A = in rows, B = W^T)
// qp/kp layout: [n*H+h][s][64] bf16.   vpT layout: [n*H+h][d][s] bf16.
// q is pre-scaled by log2(e)/32 (softmax scale folded in, log2 domain).
// ---------------------------------------------------------------------------
#define QSCL 0.04508422002778011f  // log2(e) / sqrt(EMBED)

__global__ __launch_bounds__(64) void k_proj(
    const float* __restrict__ values, const float* __restrict__ keys,
    const float* __restrict__ query,
    const float* __restrict__ Wv, const float* __restrict__ Wq,
    const float* __restrict__ Wk,
    short* __restrict__ qp, short* __restrict__ kp, short* __restrict__ vpT) {
  const int r0 = blockIdx.x * 16;     // row over B*S
  const int h  = blockIdx.y;
  const int z  = blockIdx.z;          // 0=q, 1=k, 2=v
  const float* in_; const float* W;
  if (z == 0)      { in_ = query;  W = Wq; }
  else if (z == 1) { in_ = keys;   W = Wk; }
  else             { in_ = values; W = Wv; }
  const int l = threadIdx.x, lr = l & 15, g = l >> 4;
  const int n = r0 >> 10, s0 = r0 & 1023;
  const int nh = n * HEADS + h;

  float4v acc[4];
  for (int nt = 0; nt < 4; ++nt) acc[nt] = (float4v){0.f, 0.f, 0.f, 0.f};

  for (int kb = 0; kb < 2; ++kb) {
    short8 af = cvt8(in_ + (size_t)(r0 + lr) * EMBED + h * HDIM + kb * 32 + g * 8);
    for (int nt = 0; nt < 4; ++nt) {
      short8 bf = cvt8(W + (size_t)(nt * 16 + lr) * HDIM + kb * 32 + g * 8);
      acc[nt] = __builtin_amdgcn_mfma_f32_16x16x32_bf16(af, bf, acc[nt], 0, 0, 0);
    }
  }
  // D layout: row = g*4+i, col = lr
  if (z == 2) {
    for (int nt = 0; nt < 4; ++nt) {
      short4v r;
      r[0]=f2b(acc[nt][0]); r[1]=f2b(acc[nt][1]);
      r[2]=f2b(acc[nt][2]); r[3]=f2b(acc[nt][3]);
      *(short4v*)(vpT + (size_t)(nh * HDIM + nt * 16 + lr) * SEQ + s0 + g * 4) = r;
    }
  } else {
    short* outp = (z == 0) ? qp : kp;
    const float scl = (z == 0) ? QSCL : 1.0f;
    for (int nt = 0; nt < 4; ++nt)
      for (int i = 0; i < 4; ++i)
        outp[(size_t)(nh * SEQ + s0 + g * 4 + i) * HDIM + nt * 16 + lr] =
            f2b(acc[nt][i] * scl);
  }
}

// ---------------------------------------------------------------------------
// Kernel 2: compress mask (B,1,S,S) int32 -> bitmask (bit=1 means keep)
// ---------------------------------------------------------------------------
__global__ __launch_bounds__(256) void k_maskbits(const int* __restrict__ mask,
                                                  unsigned* __restrict__ mbits) {
  int tid = blockIdx.x * 256 + threadIdx.x;
  int v = mask[tid];
  unsigned long long bal = __ballot(v != 0);
  int l = threadIdx.x & 63;
  if ((l & 31) == 0) mbits[tid >> 5] = (unsigned)(bal >> (l & 32));
}

// ---------------------------------------------------------------------------
// Kernel 3: Wu -> bf16
// ---------------------------------------------------------------------------
__global__ __launch_bounds__(256) void k_wcvt(const float* __restrict__ Wu,
                                              short* __restrict__ wub) {
  int i4 = (blockIdx.x * 256 + threadIdx.x) * 4;
  float4v v = *(const float4v*)(Wu + i4);
  short4v r; r[0]=f2b(v[0]); r[1]=f2b(v[1]); r[2]=f2b(v[2]); r[3]=f2b(v[3]);
  *(short4v*)(wub + i4) = r;
}

// ---------------------------------------------------------------------------
// Kernel 4: flash attention, swapped-operand form.
// 1 wave per (n, h, 16 q-rows); KVBLK=64.
// S^T = mfma(K,Q): lane (lr,g) holds S^T[key=a*16+g*4+i][q=lr] -> per-lane
// scalar m/l (row = lr), in-register row ops, defer-max (THR=8, log2 domain),
// mask applied multiplicatively after exp2.  O^T accum: rescale lane-uniform.
// ---------------------------------------------------------------------------
#define PST 72  // plds stride in shorts (144B = 16B-aligned rows, conflict-free)

__global__ __launch_bounds__(64) void k_attn(
    const short* __restrict__ qp, const short* __restrict__ kp,
    const short* __restrict__ vpT, const unsigned* __restrict__ mbits,
    short* __restrict__ ao) {
  const int q0 = blockIdx.x * 16;
  const int h = blockIdx.y, n = blockIdx.z;
  const int l = threadIdx.x, lr = l & 15, g = l >> 4;
  const int nh = n * HEADS + h;
  const short* qb  = qp  + (size_t)nh * SEQ * HDIM;
  const short* kbp = kp  + (size_t)nh * SEQ * HDIM;
  const short* vb  = vpT + (size_t)nh * HDIM * SEQ;
  const unsigned* mrow = mbits + (size_t)(n * SEQ + q0 + lr) * 32;

  // Q fragments (B-operand): lane holds Q[q=lr][d=g*8+j]
  short8 qf0 = *(const short8*)(qb + (q0 + lr) * HDIM + g * 8);
  short8 qf1 = *(const short8*)(qb + (q0 + lr) * HDIM + 32 + g * 8);

  // O^T accumulators: accd[dt][i] = O^T[d=dt*16+g*4+i][q=lr]
  float4v accd[4];
  for (int dt = 0; dt < 4; ++dt) accd[dt] = (float4v){0.f, 0.f, 0.f, 0.f};
  float m_i = -3.0e18f, l_i = 0.f;   // per-lane (row q=lr), log2 domain

  __shared__ __align__(16) short plds[16 * PST];

  for (int kt = 0; kt < SEQ; kt += 64) {
    // ---- S^T = K·Q^T : sT[a][i] = S^T[key=a*16+g*4+i][q=lr]
    float4v sT[4];
    for (int a = 0; a < 4; ++a) {
      const short* kr = kbp + (size_t)(kt + a * 16 + lr) * HDIM;
      short8 kf0 = *(const short8*)(kr + g * 8);
      short8 kf1 = *(const short8*)(kr + 32 + g * 8);
      float4v z = (float4v){0.f, 0.f, 0.f, 0.f};
      z = __builtin_amdgcn_mfma_f32_16x16x32_bf16(kf0, qf0, z, 0, 0, 0);
      sT[a] = __builtin_amdgcn_mfma_f32_16x16x32_bf16(kf1, qf1, z, 0, 0, 0);
    }
    // ---- local max over this lane's 16 logits (masked values included: exact)
    float lm = sT[0][0];
    for (int a = 0; a < 4; ++a)
      for (int i = 0; i < 4; ++i) lm = fmaxf(lm, sT[a][i]);
    // ---- defer-max: rescale only when some row's max grew past THR
    if (__any(lm > m_i + 8.0f)) {
      float tm = lm;
      tm = fmaxf(tm, __shfl_xor(tm, 16, 64));
      tm = fmaxf(tm, __shfl_xor(tm, 32, 64));
      float mn = fmaxf(m_i, tm);
      float sc = exp2f(m_i - mn);
      m_i = mn;
      l_i *= sc;
      for (int dt = 0; dt < 4; ++dt)
        for (int i = 0; i < 4; ++i) accd[dt][i] *= sc;
    }
    // ---- mask words for row q0+lr, keys kt..kt+63
    uint2 mw = *(const uint2*)(mrow + (kt >> 5));
    unsigned t0 = mw.x >> (g * 4);   // a=0: bit i, a=1: bit 16+i
    unsigned t1 = mw.y >> (g * 4);   // a=2: bit i, a=3: bit 16+i
    // ---- p = exp2(s - m) * maskbit; partial row-sum; pack -> LDS (P^T -> P)
    __syncthreads();
    float psum = 0.f;
    for (int a = 0; a < 4; ++a) {
      unsigned ta = ((a & 2) ? t1 : t0) >> ((a & 1) * 16);
      float p[4];
      for (int i = 0; i < 4; ++i) {
        float v = exp2f(sT[a][i] - m_i);
        v = ((ta >> i) & 1u) ? v : 0.f;
        p[i] = v;
        psum += v;
      }
      uint2 pk; pk.x = pkbf(p[0], p[1]); pk.y = pkbf(p[2], p[3]);
      *(uint2*)(plds + lr * PST + a * 16 + g * 4) = pk;
    }
    l_i += psum;
    __syncthreads();
    // ---- O^T += V^T · P^T  (A = V^T frag, B = P frag read from LDS)
    for (int h2 = 0; h2 < 2; ++h2) {
      short8 pa = *(const short8*)(plds + lr * PST + h2 * 32 + g * 8);
      for (int dt = 0; dt < 4; ++dt) {
        short8 vf = *(const short8*)(vb + (size_t)(dt * 16 + lr) * SEQ + kt + h2 * 32 + g * 8);
        accd[dt] = __builtin_amdgcn_mfma_f32_16x16x32_bf16(vf, pa, accd[dt], 0, 0, 0);
      }
    }
  }
  // ---- epilogue: full row sum, divide, store O (4x 8B vector stores)
  l_i += __shfl_xor(l_i, 16, 64);
  l_i += __shfl_xor(l_i, 32, 64);
  float inv = 1.f / fmaxf(l_i, 1e-35f);
  short* aorow = ao + (size_t)(n * SEQ + q0 + lr) * EMBED + h * HDIM;
  for (int dt = 0; dt < 4; ++dt) {
    short4v r;
    r[0] = f2b(accd[dt][0] * inv);
    r[1] = f2b(accd[dt][1] * inv);
    r[2] = f2b(accd[dt][2] * inv);
    r[3] = f2b(accd[dt][3] * inv);
    *(short4v*)(aorow + dt * 16 + g * 4) = r;
  }
}

// ---------------------------------------------------------------------------
// Kernel 5: out = ao @ Wu^T + bu.  64x64 tile, 4 waves, LDS-staged bf16 tiles
// with stride-40 (bf16) padding.
// ---------------------------------------------------------------------------
__global__ __launch_bounds__(256) void k_gemm(
    const short* __restrict__ ao, const short* __restrict__ wub,
    const float* __restrict__ bu, float* __restrict__ out) {
  const int r0 = blockIdx.x * 64, c0 = blockIdx.y * 64;
  const int t = threadIdx.x;
  const int w = t >> 6, l = t & 63, lr = l & 15, g = l >> 4;
  __shared__ __align__(16) short albuf[64 * 40];
  __shared__ __align__(16) short blbuf[64 * 40];
  float4v acc[4];
  for (int nt = 0; nt < 4; ++nt) acc[nt] = (float4v){0.f, 0.f, 0.f, 0.f};
  const int lrow = t >> 2, lcb = (t & 3) * 8;
  for (int kbk = 0; kbk < EMBED; kbk += 32) {
    __syncthreads();
    *(short8*)(albuf + lrow * 40 + lcb) =
        *(const short8*)(ao + (size_t)(r0 + lrow) * EMBED + kbk + lcb);
    *(short8*)(blbuf + lrow * 40 + lcb) =
        *(const short8*)(wub + (size_t)(c0 + lrow) * EMBED + kbk + lcb);
    __syncthreads();
    short8 af = *(const short8*)(albuf + (16 * w + lr) * 40 + g * 8);
    for (int nt = 0; nt < 4; ++nt) {
      short8 bf = *(const short8*)(blbuf + (nt * 16 + lr) * 40 + g * 8);
      acc[nt] = __builtin_amdgcn_mfma_f32_16x16x32_bf16(af, bf, acc[nt], 0, 0, 0);
    }
  }
  for (int nt = 0; nt < 4; ++nt)
    for (int i = 0; i < 4; ++i) {
      int row = r0 + 16 * w + g * 4 + i;
      int col = c0 + nt * 16 + lr;
      out[(size_t)row * EMBED + col] = acc[nt][i] + bu[col];
    }
}

// ---------------------------------------------------------------------------
extern "C" void kernel_launch(void* const* d_in, const int* in_sizes, int n_in,
                              void* d_out, int out_size, void* d_ws, size_t ws_size,
                              hipStream_t stream) {
  const float* values = (const float*)d_in[0];
  const float* keys   = (const float*)d_in[1];
  const float* query  = (const float*)d_in[2];
  const int*   mask   = (const int*)d_in[3];
  const float* Wv     = (const float*)d_in[4];
  const float* Wq     = (const float*)d_in[5];
  const float* Wk     = (const float*)d_in[6];
  const float* Wu     = (const float*)d_in[7];
  const float* bu     = (const float*)d_in[8];
  float* out = (float*)d_out;

  char* ws = (char*)d_ws;
  short* qp  = (short*)ws;                        // 8 MB  (4M bf16)
  short* kp  = qp + (1u << 22);                   // 8 MB
  short* vpT = kp + (1u << 22);                   // 8 MB (transposed V)
  short* ao  = vpT + (1u << 22);                  // 8 MB
  unsigned* mbits = (unsigned*)(ws + (32u << 20));        // 512 KB
  short* wub = (short*)(ws + (32u << 20) + (512u << 10)); // 2 MB

  k_proj<<<dim3(256, 16, 3), 64, 0, stream>>>(values, keys, query, Wv, Wq, Wk,
                                              qp, kp, vpT);
  k_maskbits<<<dim3(16384), 256, 0, stream>>>(mask, mbits);
  k_wcvt<<<dim3(1024), 256, 0, stream>>>(Wu, wub);
  k_attn<<<dim3(64, 16, 4), 64, 0, stream>>>(qp, kp, vpT, mbits, ao);
  k_gemm<<<dim3(64, 16), 256, 0, stream>>>(ao, wub, bu, out);
}

// Round 4
// 114.476 us; speedup vs baseline: 1.7134x; 1.7134x over previous
//
#include <hip/hip_runtime.h>
#include <hip/hip_bf16.h>

#define EMBED 1024
#define HEADS 16
#define HDIM  64
#define BATCH 4
#define SEQ   1024

typedef __attribute__((ext_vector_type(8))) short  short8;
typedef __attribute__((ext_vector_type(4))) short  short4v;
typedef __attribute__((ext_vector_type(4))) float  float4v;

// f32 -> bf16 (RNE)
static __device__ __forceinline__ short f2b(float f) {
  unsigned u = __builtin_bit_cast(unsigned, f);
  unsigned r = (u + 0x7FFFu + ((u >> 16) & 1u)) >> 16;
  return (short)(unsigned short)r;
}

// pack two f32 -> bf16x2 (RNE) in one dword (lo = a, hi = b)
static __device__ __forceinline__ unsigned pkbf(float a, float b) {
  float2 t; t.x = a; t.y = b;
  __hip_bfloat162 h = __float22bfloat162_rn(t);
  unsigned u; __builtin_memcpy(&u, &h, 4);
  return u;
}

static __device__ __forceinline__ short8 cvt8(const float* p) {
  float4v a = *(const float4v*)p;
  float4v b = *(const float4v*)(p + 4);
  short8 r;
  r[0]=f2b(a[0]); r[1]=f2b(a[1]); r[2]=f2b(a[2]); r[3]=f2b(a[3]);
  r[4]=f2b(b[0]); r[5]=f2b(b[1]); r[6]=f2b(b[2]); r[7]=f2b(b[3]);
  return r;
}

// ---------------------------------------------------------------------------
// Kernel 1: per-head projections q/k/v.  1 wave per (16 rows, head, tensor).
// qp/kp layout: [n*H+h][s][64] bf16.   vpT layout: [n*H+h][d][s] bf16.
// q pre-scaled by log2(e)/32 (softmax scale folded, log2 domain).
// ---------------------------------------------------------------------------
#define QSCL 0.04508422002778011f  // log2(e) / sqrt(EMBED)

__global__ __launch_bounds__(64) void k_proj(
    const float* __restrict__ values, const float* __restrict__ keys,
    const float* __restrict__ query,
    const float* __restrict__ Wv, const float* __restrict__ Wq,
    const float* __restrict__ Wk,
    short* __restrict__ qp, short* __restrict__ kp, short* __restrict__ vpT) {
  const int r0 = blockIdx.x * 16;     // row over B*S
  const int h  = blockIdx.y;
  const int z  = blockIdx.z;          // 0=q, 1=k, 2=v
  const float* in_; const float* W;
  if (z == 0)      { in_ = query;  W = Wq; }
  else if (z == 1) { in_ = keys;   W = Wk; }
  else             { in_ = values; W = Wv; }
  const int l = threadIdx.x, lr = l & 15, g = l >> 4;
  const int n = r0 >> 10, s0 = r0 & 1023;
  const int nh = n * HEADS + h;

  float4v acc[4];
  for (int nt = 0; nt < 4; ++nt) acc[nt] = (float4v){0.f, 0.f, 0.f, 0.f};

  for (int kb = 0; kb < 2; ++kb) {
    short8 af = cvt8(in_ + (size_t)(r0 + lr) * EMBED + h * HDIM + kb * 32 + g * 8);
    for (int nt = 0; nt < 4; ++nt) {
      short8 bf = cvt8(W + (size_t)(nt * 16 + lr) * HDIM + kb * 32 + g * 8);
      acc[nt] = __builtin_amdgcn_mfma_f32_16x16x32_bf16(af, bf, acc[nt], 0, 0, 0);
    }
  }
  // D layout: row = g*4+i, col = lr
  if (z == 2) {
    for (int nt = 0; nt < 4; ++nt) {
      short4v r;
      r[0]=f2b(acc[nt][0]); r[1]=f2b(acc[nt][1]);
      r[2]=f2b(acc[nt][2]); r[3]=f2b(acc[nt][3]);
      *(short4v*)(vpT + (size_t)(nh * HDIM + nt * 16 + lr) * SEQ + s0 + g * 4) = r;
    }
  } else {
    short* outp = (z == 0) ? qp : kp;
    const float scl = (z == 0) ? QSCL : 1.0f;
    for (int nt = 0; nt < 4; ++nt)
      for (int i = 0; i < 4; ++i)
        outp[(size_t)(nh * SEQ + s0 + g * 4 + i) * HDIM + nt * 16 + lr] =
            f2b(acc[nt][i] * scl);
  }
}

// ---------------------------------------------------------------------------
// Kernel 2: compress mask (B,1,S,S) int32 -> bitmask (bit=1 means keep)
// ---------------------------------------------------------------------------
__global__ __launch_bounds__(256) void k_maskbits(const int* __restrict__ mask,
                                                  unsigned* __restrict__ mbits) {
  int tid = blockIdx.x * 256 + threadIdx.x;
  int v = mask[tid];
  unsigned long long bal = __ballot(v != 0);
  int l = threadIdx.x & 63;
  if ((l & 31) == 0) mbits[tid >> 5] = (unsigned)(bal >> (l & 32));
}

// ---------------------------------------------------------------------------
// Kernel 3: Wu -> bf16
// ---------------------------------------------------------------------------
__global__ __launch_bounds__(256) void k_wcvt(const float* __restrict__ Wu,
                                              short* __restrict__ wub) {
  int i4 = (blockIdx.x * 256 + threadIdx.x) * 4;
  float4v v = *(const float4v*)(Wu + i4);
  short4v r; r[0]=f2b(v[0]); r[1]=f2b(v[1]); r[2]=f2b(v[2]); r[3]=f2b(v[3]);
  *(short4v*)(wub + i4) = r;
}

// ---------------------------------------------------------------------------
// Kernel 4: flash attention, 4-wave blocks (QBLK=64), LDS-staged K/V.
// K/V tiles (64 keys) double-buffered in LDS, reg-staged (loads issued at
// tile top, ds_write at tile end, one __syncthreads per tile = lgkm drain).
// 16B-block XOR swizzle (blk ^= row&7) -> conflict-minimal b128 reads.
// Per-wave swapped-operand softmax (S^T=K*Q^T), defer-max THR=8, log2 domain,
// multiplicative mask, O^T accumulation, P via per-wave 16x40 LDS (half-reuse).
// ---------------------------------------------------------------------------
__global__ __launch_bounds__(256, 4) void k_attn(
    const short* __restrict__ qp, const short* __restrict__ kp,
    const short* __restrict__ vpT, const unsigned* __restrict__ mbits,
    short* __restrict__ ao) {
  const int h = blockIdx.y, n = blockIdx.z;
  const int t256 = threadIdx.x;
  const int w = t256 >> 6, l = t256 & 63, lr = l & 15, g = l >> 4;
  const int nh = n * HEADS + h;
  const int q0 = blockIdx.x * 64 + w * 16;
  const short* qb  = qp  + (size_t)nh * SEQ * HDIM;
  const short* kbp = kp  + (size_t)nh * SEQ * HDIM;
  const short* vb  = vpT + (size_t)nh * HDIM * SEQ;
  const unsigned* mrow = mbits + (size_t)(n * SEQ + q0 + lr) * 32;

  __shared__ __align__(16) short kls[2][4096];   // K tile [row 64][64], swizzled
  __shared__ __align__(16) short vls[2][4096];   // V^T tile [d 64][64], swizzled
  __shared__ __align__(16) short plds[4][16 * 40];
  short* pw = plds[w];

  // staging slots: thread handles slots t256 and t256+256 (16B each)
  const int s0 = t256, s1 = t256 + 256;
  const int r0s = s0 >> 3, c0s = s0 & 7, r1s = s1 >> 3, c1s = s1 & 7;
  const int ld0 = r0s * 64 + ((c0s ^ (r0s & 7)) << 3);   // swizzled LDS dest
  const int ld1 = r1s * 64 + ((c1s ^ (r1s & 7)) << 3);

  // ---- prologue: stage tile 0
  short8 stK0 = *(const short8*)(kbp + s0 * 8);
  short8 stK1 = *(const short8*)(kbp + s1 * 8);
  short8 stV0 = *(const short8*)(vb + (size_t)r0s * SEQ + c0s * 8);
  short8 stV1 = *(const short8*)(vb + (size_t)r1s * SEQ + c1s * 8);
  *(short8*)(kls[0] + ld0) = stK0;
  *(short8*)(kls[0] + ld1) = stK1;
  *(short8*)(vls[0] + ld0) = stV0;
  *(short8*)(vls[0] + ld1) = stV1;

  // Q fragments (B-operand): lane holds Q[q=lr][d=g*8+j]
  short8 qf0 = *(const short8*)(qb + (q0 + lr) * HDIM + g * 8);
  short8 qf1 = *(const short8*)(qb + (q0 + lr) * HDIM + 32 + g * 8);

  float4v accd[4];
  for (int dt = 0; dt < 4; ++dt) accd[dt] = (float4v){0.f, 0.f, 0.f, 0.f};
  float m_i = -3.0e18f, l_i = 0.f;   // per-lane (row q=lr), log2 domain

  __syncthreads();

  for (int t = 0; t < 16; ++t) {
    const int kt = t * 64;
    // ---- issue prefetch of tile t+1 (overlaps with compute below)
    if (t < 15) {
      const int kn = kt + 64;
      stK0 = *(const short8*)(kbp + kn * 64 + s0 * 8);
      stK1 = *(const short8*)(kbp + kn * 64 + s1 * 8);
      stV0 = *(const short8*)(vb + (size_t)r0s * SEQ + kn + c0s * 8);
      stV1 = *(const short8*)(vb + (size_t)r1s * SEQ + kn + c1s * 8);
    }
    const short* Kb = kls[t & 1];
    const short* Vb = vls[t & 1];
    // ---- S^T = K·Q^T : sT[a][i] = S^T[key=a*16+g*4+i][q=lr]
    float4v sT[4];
    for (int a = 0; a < 4; ++a) {
      int row = a * 16 + lr;
      short8 kf0 = *(const short8*)(Kb + row * 64 + ((g ^ (row & 7)) << 3));
      short8 kf1 = *(const short8*)(Kb + row * 64 + (((4 + g) ^ (row & 7)) << 3));
      float4v z = (float4v){0.f, 0.f, 0.f, 0.f};
      z = __builtin_amdgcn_mfma_f32_16x16x32_bf16(kf0, qf0, z, 0, 0, 0);
      sT[a] = __builtin_amdgcn_mfma_f32_16x16x32_bf16(kf1, qf1, z, 0, 0, 0);
    }
    // ---- local max over this lane's 16 logits (masked included: exact)
    float m01 = fmaxf(fmaxf(sT[0][0], sT[0][1]), fmaxf(sT[0][2], sT[0][3]));
    float m11 = fmaxf(fmaxf(sT[1][0], sT[1][1]), fmaxf(sT[1][2], sT[1][3]));
    float m21 = fmaxf(fmaxf(sT[2][0], sT[2][1]), fmaxf(sT[2][2], sT[2][3]));
    float m31 = fmaxf(fmaxf(sT[3][0], sT[3][1]), fmaxf(sT[3][2], sT[3][3]));
    float lm = fmaxf(fmaxf(m01, m11), fmaxf(m21, m31));
    // ---- defer-max: rescale only when some row's max grew past THR
    if (__any(lm > m_i + 8.0f)) {
      float tm = lm;
      tm = fmaxf(tm, __shfl_xor(tm, 16, 64));
      tm = fmaxf(tm, __shfl_xor(tm, 32, 64));
      float mn = fmaxf(m_i, tm);
      float sc = exp2f(m_i - mn);
      m_i = mn;
      l_i *= sc;
      for (int dt = 0; dt < 4; ++dt)
        for (int i = 0; i < 4; ++i) accd[dt][i] *= sc;
    }
    // ---- mask words for row q0+lr, keys kt..kt+63
    uint2 mw = *(const uint2*)(mrow + (kt >> 5));
    unsigned t0m = mw.x >> (g * 4);
    unsigned t1m = mw.y >> (g * 4);
    // ---- two 32-key halves: exp2 + pack -> P buffer -> PV MFMA
    float psum = 0.f;
    for (int h2 = 0; h2 < 2; ++h2) {
      for (int ah = 0; ah < 2; ++ah) {
        int a = h2 * 2 + ah;
        unsigned ta = ((a & 2) ? t1m : t0m) >> ((a & 1) * 16);
        float p[4];
        for (int i = 0; i < 4; ++i) {
          float v = exp2f(sT[a][i] - m_i);
          v = ((ta >> i) & 1u) ? v : 0.f;
          p[i] = v;
          psum += v;
        }
        uint2 pk; pk.x = pkbf(p[0], p[1]); pk.y = pkbf(p[2], p[3]);
        *(uint2*)(pw + lr * 40 + ah * 16 + g * 4) = pk;
      }
      short8 pa = *(const short8*)(pw + lr * 40 + g * 8);
      for (int dt = 0; dt < 4; ++dt) {
        int row = dt * 16 + lr;
        short8 vf = *(const short8*)(Vb + row * 64 + (((h2 * 4 + g) ^ (row & 7)) << 3));
        accd[dt] = __builtin_amdgcn_mfma_f32_16x16x32_bf16(vf, pa, accd[dt], 0, 0, 0);
      }
    }
    l_i += psum;
    // ---- write prefetched tile to the other buffer, then barrier
    if (t < 15) {
      short* kd = kls[(t + 1) & 1];
      short* vd = vls[(t + 1) & 1];
      *(short8*)(kd + ld0) = stK0;
      *(short8*)(kd + ld1) = stK1;
      *(short8*)(vd + ld0) = stV0;
      *(short8*)(vd + ld1) = stV1;
      __syncthreads();   // drains lgkm+vm, publishes buffers to all waves
    }
  }
  // ---- epilogue: full row sum, divide, store O (4x 8B vector stores)
  l_i += __shfl_xor(l_i, 16, 64);
  l_i += __shfl_xor(l_i, 32, 64);
  float inv = 1.f / fmaxf(l_i, 1e-35f);
  short* aorow = ao + (size_t)(n * SEQ + q0 + lr) * EMBED + h * HDIM;
  for (int dt = 0; dt < 4; ++dt) {
    short4v r;
    r[0] = f2b(accd[dt][0] * inv);
    r[1] = f2b(accd[dt][1] * inv);
    r[2] = f2b(accd[dt][2] * inv);
    r[3] = f2b(accd[dt][3] * inv);
    *(short4v*)(aorow + dt * 16 + g * 4) = r;
  }
}

// ---------------------------------------------------------------------------
// Kernel 5: out = ao @ Wu^T + bu.  64x64 tile, 4 waves, LDS-staged bf16 tiles
// with stride-40 (bf16) padding.
// ---------------------------------------------------------------------------
__global__ __launch_bounds__(256) void k_gemm(
    const short* __restrict__ ao, const short* __restrict__ wub,
    const float* __restrict__ bu, float* __restrict__ out) {
  const int r0 = blockIdx.x * 64, c0 = blockIdx.y * 64;
  const int t = threadIdx.x;
  const int w = t >> 6, l = t & 63, lr = l & 15, g = l >> 4;
  __shared__ __align__(16) short albuf[64 * 40];
  __shared__ __align__(16) short blbuf[64 * 40];
  float4v acc[4];
  for (int nt = 0; nt < 4; ++nt) acc[nt] = (float4v){0.f, 0.f, 0.f, 0.f};
  const int lrow = t >> 2, lcb = (t & 3) * 8;
  for (int kbk = 0; kbk < EMBED; kbk += 32) {
    __syncthreads();
    *(short8*)(albuf + lrow * 40 + lcb) =
        *(const short8*)(ao + (size_t)(r0 + lrow) * EMBED + kbk + lcb);
    *(short8*)(blbuf + lrow * 40 + lcb) =
        *(const short8*)(wub + (size_t)(c0 + lrow) * EMBED + kbk + lcb);
    __syncthreads();
    short8 af = *(const short8*)(albuf + (16 * w + lr) * 40 + g * 8);
    for (int nt = 0; nt < 4; ++nt) {
      short8 bf = *(const short8*)(blbuf + (nt * 16 + lr) * 40 + g * 8);
      acc[nt] = __builtin_amdgcn_mfma_f32_16x16x32_bf16(af, bf, acc[nt], 0, 0, 0);
    }
  }
  for (int nt = 0; nt < 4; ++nt)
    for (int i = 0; i < 4; ++i) {
      int row = r0 + 16 * w + g * 4 + i;
      int col = c0 + nt * 16 + lr;
      out[(size_t)row * EMBED + col] = acc[nt][i] + bu[col];
    }
}

// ---------------------------------------------------------------------------
extern "C" void kernel_launch(void* const* d_in, const int* in_sizes, int n_in,
                              void* d_out, int out_size, void* d_ws, size_t ws_size,
                              hipStream_t stream) {
  const float* values = (const float*)d_in[0];
  const float* keys   = (const float*)d_in[1];
  const float* query  = (const float*)d_in[2];
  const int*   mask   = (const int*)d_in[3];
  const float* Wv     = (const float*)d_in[4];
  const float* Wq     = (const float*)d_in[5];
  const float* Wk     = (const float*)d_in[6];
  const float* Wu     = (const float*)d_in[7];
  const float* bu     = (const float*)d_in[8];
  float* out = (float*)d_out;

  char* ws = (char*)d_ws;
  short* qp  = (short*)ws;                        // 8 MB  (4M bf16)
  short* kp  = qp + (1u << 22);                   // 8 MB
  short* vpT = kp + (1u << 22);                   // 8 MB (transposed V)
  short* ao  = vpT + (1u << 22);                  // 8 MB
  unsigned* mbits = (unsigned*)(ws + (32u << 20));        // 512 KB
  short* wub = (short*)(ws + (32u << 20) + (512u << 10)); // 2 MB

  k_proj<<<dim3(256, 16, 3), 64, 0, stream>>>(values, keys, query, Wv, Wq, Wk,
                                              qp, kp, vpT);
  k_maskbits<<<dim3(16384), 256, 0, stream>>>(mask, mbits);
  k_wcvt<<<dim3(1024), 256, 0, stream>>>(Wu, wub);
  k_attn<<<dim3(16, 16, 4), 256, 0, stream>>>(qp, kp, vpT, mbits, ao);
  k_gemm<<<dim3(64, 16), 256, 0, stream>>>(ao, wub, bu, out);
}